// Round 1
// baseline (280.723 us; speedup 1.0000x reference)
//
#include <hip/hip_runtime.h>

#define LDIM 256
#define PDIM 128
#define NHEAD 4
#define DHEAD 32
#define NPOS (LDIM*LDIM)   // 65536

typedef __attribute__((ext_vector_type(8))) short bf16x8;
typedef __attribute__((ext_vector_type(4))) float f32x4;

static __device__ __forceinline__ unsigned short f2bf(float f) {
  union { float f; unsigned int u; } v; v.f = f;
  unsigned int r = v.u + 0x7fffu + ((v.u >> 16) & 1u);
  return (unsigned short)(r >> 16);
}
static __device__ __forceinline__ float bf2f(unsigned short u) {
  union { unsigned int u; float f; } v; v.u = ((unsigned int)u) << 16;
  return v.f;
}

// ---------------- K0: pack transposed bf16 weights ----------------
// WT[n][k], n in [0,512): 0-127 Wq^T * (1/sqrt(32)), 128-255 Wk^T, 256-383 Wv^T, 384-511 Wg^T
// WoT[n][k] = Wo[k][n]
__global__ void k_pack(const float* __restrict__ Wq, const float* __restrict__ Wk,
                       const float* __restrict__ Wv, const float* __restrict__ Wg,
                       const float* __restrict__ Wo,
                       ushort* __restrict__ WT, ushort* __restrict__ WoT) {
  int idx = blockIdx.x * blockDim.x + threadIdx.x;
  if (idx < 512 * 128) {
    int n = idx >> 7, k = idx & 127;
    int nn = n & 127;
    float val;
    if (n < 128)      val = Wq[k * 128 + nn] * 0.17677669529663687f; // fold 1/sqrt(D)
    else if (n < 256) val = Wk[k * 128 + nn];
    else if (n < 384) val = Wv[k * 128 + nn];
    else              val = Wg[k * 128 + nn];
    WT[idx] = f2bf(val);
  } else if (idx < 512 * 128 + 128 * 128) {
    int j = idx - 512 * 128;
    int n = j >> 7, k = j & 127;
    WoT[j] = f2bf(Wo[k * 128 + n]);
  }
}

// ---------------- K1: LayerNorm -> x (bf16) + pairwise bias ----------------
// one wave per position; bias[h][pos] = sum_p xn[p] * Wb[p][h]
__global__ __launch_bounds__(256) void k_ln_bias(
    const float* __restrict__ in, const float* __restrict__ gamma,
    const float* __restrict__ beta, const float* __restrict__ Wb,
    ushort* __restrict__ x, float* __restrict__ biasg) {
  int wv = threadIdx.x >> 6;
  int lane = threadIdx.x & 63;
  int pos = blockIdx.x * 4 + wv;
  const float* row = in + (size_t)pos * 128;
  float a = row[lane], b = row[lane + 64];
  float s = a + b, ss = a * a + b * b;
  #pragma unroll
  for (int m = 1; m < 64; m <<= 1) {
    s  += __shfl_xor(s, m, 64);
    ss += __shfl_xor(ss, m, 64);
  }
  float mu  = s * (1.0f / 128.0f);
  float var = ss * (1.0f / 128.0f) - mu * mu;
  float rs  = rsqrtf(var + 1e-5f);
  float xa = (a - mu) * rs * gamma[lane]      + beta[lane];
  float xb = (b - mu) * rs * gamma[lane + 64] + beta[lane + 64];
  x[(size_t)pos * 128 + lane]      = f2bf(xa);
  x[(size_t)pos * 128 + lane + 64] = f2bf(xb);
  float b0 = xa * Wb[lane * 4 + 0] + xb * Wb[(lane + 64) * 4 + 0];
  float b1 = xa * Wb[lane * 4 + 1] + xb * Wb[(lane + 64) * 4 + 1];
  float b2 = xa * Wb[lane * 4 + 2] + xb * Wb[(lane + 64) * 4 + 2];
  float b3 = xa * Wb[lane * 4 + 3] + xb * Wb[(lane + 64) * 4 + 3];
  #pragma unroll
  for (int m = 1; m < 64; m <<= 1) {
    b0 += __shfl_xor(b0, m, 64);
    b1 += __shfl_xor(b1, m, 64);
    b2 += __shfl_xor(b2, m, 64);
    b3 += __shfl_xor(b3, m, 64);
  }
  if (lane == 0) {
    biasg[0 * NPOS + pos] = b0;
    biasg[1 * NPOS + pos] = b1;
    biasg[2 * NPOS + pos] = b2;
    biasg[3 * NPOS + pos] = b3;
  }
}

// ---------------- K2: QKVG projection GEMM (MFMA bf16) ----------------
// C[65536 x 512] = x[65536 x 128] @ Wcat[128 x 512]
// q/k/v written as [i][h][pos][d] bf16; gate = sigmoid(.+bg) as [pos][128] bf16
__global__ __launch_bounds__(256) void k_proj(
    const ushort* __restrict__ x, const ushort* __restrict__ WT,
    const float* __restrict__ bg,
    ushort* __restrict__ q, ushort* __restrict__ kk,
    ushort* __restrict__ v, ushort* __restrict__ gate) {
  int wv = threadIdx.x >> 6, lane = threadIdx.x & 63;
  int n15 = lane & 15, g = lane >> 4;
  int m0 = blockIdx.y * 64 + wv * 16;
  bf16x8 a[4];
  #pragma unroll
  for (int kc = 0; kc < 4; kc++)
    a[kc] = *(const bf16x8*)(x + (size_t)(m0 + n15) * 128 + kc * 32 + g * 8);
  #pragma unroll
  for (int nt = 0; nt < 8; nt++) {
    int nbase = blockIdx.x * 128 + nt * 16;
    f32x4 acc = {0.f, 0.f, 0.f, 0.f};
    #pragma unroll
    for (int kc = 0; kc < 4; kc++) {
      bf16x8 b = *(const bf16x8*)(WT + (size_t)(nbase + n15) * 128 + kc * 32 + g * 8);
      acc = __builtin_amdgcn_mfma_f32_16x16x32_bf16(a[kc], b, acc, 0, 0, 0);
    }
    int col = nbase + n15;         // 0..511
    int sect = nbase >> 7;         // wave-uniform
    int cl = col & 127;
    int h = cl >> 5, d = cl & 31;
    #pragma unroll
    for (int r = 0; r < 4; r++) {
      int m = m0 + g * 4 + r;      // position
      float val = acc[r];
      if (sect == 3) {
        float gv = 1.0f / (1.0f + __expf(-(val + bg[cl])));
        gate[(size_t)m * 128 + cl] = f2bf(gv);
      } else {
        int i = m >> 8, j = m & 255;
        size_t addr = ((size_t)(i * 4 + h) * 256 + j) * 32 + d;
        if (sect == 0)      q[addr]  = f2bf(val);
        else if (sect == 1) kk[addr] = f2bf(val);
        else                v[addr]  = f2bf(val);
      }
    }
  }
}

// ---------------- K3: attention per (i,h) ----------------
#define SV 264
#define SP 264
__global__ __launch_bounds__(256) void k_attn(
    const ushort* __restrict__ q, const ushort* __restrict__ kmat,
    const ushort* __restrict__ vmat, const float* __restrict__ biasg,
    const ushort* __restrict__ gate, ushort* __restrict__ gctx) {
  __shared__ __align__(16) ushort VT[32 * SV];       // V^T: [d][kpos]
  __shared__ __align__(16) ushort Psh[4][16 * SP];   // per-wave P tile [16 x 256]
  int i = blockIdx.x >> 2;
  int h = blockIdx.x & 3;
  int tid = threadIdx.x, wv = tid >> 6, lane = tid & 63;
  int n = lane & 15, g = lane >> 4;
  const ushort* qh = q    + (size_t)(i * 4 + h) * 256 * 32;
  const ushort* kh = kmat + (size_t)(i * 4 + h) * 256 * 32;
  const ushort* vh = vmat + (size_t)(i * 4 + h) * 256 * 32;
  // stage V transposed into LDS (thread t handles key position t)
  {
    const bf16x8* src = (const bf16x8*)(vh + (size_t)tid * 32);
    bf16x8 e0 = src[0], e1 = src[1], e2 = src[2], e3 = src[3];
    #pragma unroll
    for (int d = 0; d < 8; d++) {
      VT[(d)      * SV + tid] = (ushort)e0[d];
      VT[(d + 8)  * SV + tid] = (ushort)e1[d];
      VT[(d + 16) * SV + tid] = (ushort)e2[d];
      VT[(d + 24) * SV + tid] = (ushort)e3[d];
    }
  }
  __syncthreads();
  // V b-frags -> registers (reused across all j-tiles)
  bf16x8 vf[8][2];
  #pragma unroll
  for (int kc = 0; kc < 8; kc++)
    #pragma unroll
    for (int nt = 0; nt < 2; nt++)
      vf[kc][nt] = *(const bf16x8*)(&VT[(nt * 16 + n) * SV + kc * 32 + g * 8]);

  for (int jj = 0; jj < 4; jj++) {
    int j0 = (wv * 4 + jj) * 16;
    bf16x8 aq = *(const bf16x8*)(qh + (size_t)(j0 + n) * 32 + g * 8);
    f32x4 s[16];
    #pragma unroll
    for (int kt = 0; kt < 16; kt++) {
      f32x4 c;
      #pragma unroll
      for (int r = 0; r < 4; r++)
        c[r] = biasg[(size_t)h * NPOS + (size_t)(j0 + g * 4 + r) * 256 + kt * 16 + n];
      bf16x8 bk = *(const bf16x8*)(kh + (size_t)(kt * 16 + n) * 32 + g * 8);
      s[kt] = __builtin_amdgcn_mfma_f32_16x16x32_bf16(aq, bk, c, 0, 0, 0);
    }
    // softmax over the 256 keys for each of this lane-group's 4 rows
    float inv[4];
    #pragma unroll
    for (int r = 0; r < 4; r++) {
      float m = s[0][r];
      #pragma unroll
      for (int kt = 1; kt < 16; kt++) m = fmaxf(m, s[kt][r]);
      #pragma unroll
      for (int xm = 1; xm < 16; xm <<= 1) m = fmaxf(m, __shfl_xor(m, xm, 16));
      float sm = 0.f;
      #pragma unroll
      for (int kt = 0; kt < 16; kt++) {
        float p = __expf(s[kt][r] - m);
        s[kt][r] = p;
        sm += p;
      }
      #pragma unroll
      for (int xm = 1; xm < 16; xm <<= 1) sm += __shfl_xor(sm, xm, 16);
      inv[r] = 1.0f / sm;
    }
    // P -> LDS (bf16, A-frag layout round trip)
    ushort* Pw = Psh[wv];
    #pragma unroll
    for (int kt = 0; kt < 16; kt++)
      #pragma unroll
      for (int r = 0; r < 4; r++)
        Pw[(g * 4 + r) * SP + kt * 16 + n] = f2bf(s[kt][r] * inv[r]);
    __syncthreads();   // all waves loop uniformly; also orders LDS write->read
    // PV
    f32x4 ctx0 = {0.f, 0.f, 0.f, 0.f}, ctx1 = {0.f, 0.f, 0.f, 0.f};
    #pragma unroll
    for (int kc = 0; kc < 8; kc++) {
      bf16x8 ap = *(const bf16x8*)(&Pw[n * SP + kc * 32 + g * 8]);
      ctx0 = __builtin_amdgcn_mfma_f32_16x16x32_bf16(ap, vf[kc][0], ctx0, 0, 0, 0);
      ctx1 = __builtin_amdgcn_mfma_f32_16x16x32_bf16(ap, vf[kc][1], ctx1, 0, 0, 0);
    }
    // gate and write gctx [pos][128] bf16
    #pragma unroll
    for (int nt = 0; nt < 2; nt++) {
      f32x4 c = nt ? ctx1 : ctx0;
      #pragma unroll
      for (int r = 0; r < 4; r++) {
        int j = j0 + g * 4 + r;
        int pch = h * 32 + nt * 16 + n;
        size_t o = ((size_t)i * 256 + j) * 128 + pch;
        float gv = bf2f(gate[o]);
        gctx[o] = f2bf(c[r] * gv);
      }
    }
  }
}

// ---------------- K4: output projection + bias + residual ----------------
__global__ __launch_bounds__(256) void k_out(
    const ushort* __restrict__ gctx, const ushort* __restrict__ WoT,
    const float* __restrict__ bo, const float* __restrict__ in0,
    float* __restrict__ out) {
  int wv = threadIdx.x >> 6, lane = threadIdx.x & 63;
  int n15 = lane & 15, g = lane >> 4;
  int m0 = blockIdx.x * 64 + wv * 16;
  bf16x8 a[4];
  #pragma unroll
  for (int kc = 0; kc < 4; kc++)
    a[kc] = *(const bf16x8*)(gctx + (size_t)(m0 + n15) * 128 + kc * 32 + g * 8);
  #pragma unroll
  for (int nt = 0; nt < 8; nt++) {
    int nn = nt * 16 + n15;
    f32x4 acc = {0.f, 0.f, 0.f, 0.f};
    #pragma unroll
    for (int kc = 0; kc < 4; kc++) {
      bf16x8 b = *(const bf16x8*)(WoT + (size_t)nn * 128 + kc * 32 + g * 8);
      acc = __builtin_amdgcn_mfma_f32_16x16x32_bf16(a[kc], b, acc, 0, 0, 0);
    }
    #pragma unroll
    for (int r = 0; r < 4; r++) {
      int m = m0 + g * 4 + r;
      size_t o = (size_t)m * 128 + nn;
      out[o] = acc[r] + bo[nn] + in0[o];
    }
  }
}

extern "C" void kernel_launch(void* const* d_in, const int* in_sizes, int n_in,
                              void* d_out, int out_size, void* d_ws, size_t ws_size,
                              hipStream_t stream) {
  const float* in0   = (const float*)d_in[0];
  const float* gamma = (const float*)d_in[1];
  const float* beta  = (const float*)d_in[2];
  const float* Wq    = (const float*)d_in[3];
  const float* Wk    = (const float*)d_in[4];
  const float* Wv    = (const float*)d_in[5];
  const float* Wb    = (const float*)d_in[6];
  const float* Wg    = (const float*)d_in[7];
  const float* bg    = (const float*)d_in[8];
  const float* Wo    = (const float*)d_in[9];
  const float* bo    = (const float*)d_in[10];
  float* out = (float*)d_out;
  char* ws = (char*)d_ws;

  const size_t MB = 1024 * 1024;
  ushort* xbuf = (ushort*)(ws);              // 16 MB (x; later reused as gctx — stream-ordered)
  ushort* qbuf = (ushort*)(ws + 16 * MB);    // 16 MB
  ushort* kbuf = (ushort*)(ws + 32 * MB);    // 16 MB
  ushort* vbuf = (ushort*)(ws + 48 * MB);    // 16 MB
  ushort* gbuf = (ushort*)(ws + 64 * MB);    // 16 MB (gate)
  float*  bias = (float*) (ws + 80 * MB);    // 1 MB
  ushort* WT   = (ushort*)(ws + 81 * MB);    // 128 KB
  ushort* WoT  = (ushort*)(ws + 82 * MB);    // 32 KB

  k_pack<<<320, 256, 0, stream>>>(Wq, Wk, Wv, Wg, Wo, WT, WoT);
  k_ln_bias<<<16384, 256, 0, stream>>>(in0, gamma, beta, Wb, xbuf, bias);
  k_proj<<<dim3(4, 1024), 256, 0, stream>>>(xbuf, WT, bg, qbuf, kbuf, vbuf, gbuf);
  k_attn<<<1024, 256, 0, stream>>>(qbuf, kbuf, vbuf, bias, gbuf, xbuf /*gctx*/);
  k_out<<<1024, 256, 0, stream>>>(xbuf, WoT, bo, in0, out);
}